// Round 9
// baseline (195.869 us; speedup 1.0000x reference)
//
#include <hip/hip_runtime.h>
#include <math.h>

#define NCOLS 4096
#define MROWS 4096
#define NLAYERS 5
#define RPB 16                // rows per fused block
#define NSPLIT (MROWS / RPB)  // 256 column-partial splits
// stage-2: 512 blocks x 256 threads (2 blocks/CU); 8 cols/block; 32 groups x 8 splits
#define S2SP (NSPLIT / 32)

__device__ __forceinline__ float sigf(float x) { return 1.0f / (1.0f + expf(-x)); }

// bf16 (packed in 32-bit words) -> float, exact
__device__ __forceinline__ float lo16(unsigned w) { return __uint_as_float(w << 16); }
__device__ __forceinline__ float hi16(unsigned w) { return __uint_as_float(w & 0xFFFF0000u); }

// float -> bf16 bits, round-to-nearest-even (A has no NaN/Inf)
__device__ __forceinline__ unsigned f2bf(float f) {
    unsigned u = __float_as_uint(f);
    return (u + 0x7FFFu + ((u >> 16) & 1u)) >> 16;
}

__device__ __forceinline__ void unpack8(uint4 w, float* a) {
    a[0] = lo16(w.x); a[1] = hi16(w.x); a[2] = lo16(w.y); a[3] = hi16(w.y);
    a[4] = lo16(w.z); a[5] = hi16(w.z); a[6] = lo16(w.w); a[7] = hi16(w.w);
}

// ============ fused preamble: fp32 read, bf16 convert+store, rowsum->right_mask,
// ============ colsum partial p1, colmax(rm) partial p2 — ONE pass over fp32 A
__global__ __launch_bounds__(512) void k_pre_fused(
    const float* __restrict__ A, unsigned* __restrict__ Abf,
    const float* __restrict__ thqr, float* __restrict__ right_mask,
    float* __restrict__ one_r, float* __restrict__ y, float* __restrict__ p1,
    float* __restrict__ p2) {
    __shared__ float prt[RPB][512];
    __shared__ float rml[RPB];
    int t = threadIdx.x, s = blockIdx.x, r0 = s * RPB;
    int wid = t >> 6, lane = t & 63;
    const float4* a4 = reinterpret_cast<const float4*>(A);
    uint4* o4 = reinterpret_cast<uint4*>(Abf);
    uint4 w[RPB];
#pragma unroll
    for (int i = 0; i < RPB; i++) {
        size_t base = (size_t)(r0 + i) * 1024 + 2 * t;
        float4 fA = a4[base];
        float4 fB = a4[base + 1];
        prt[i][t] = ((fA.x + fA.y) + (fA.z + fA.w)) + ((fB.x + fB.y) + (fB.z + fB.w));
        uint4 u;
        u.x = f2bf(fA.x) | (f2bf(fA.y) << 16);
        u.y = f2bf(fA.z) | (f2bf(fA.w) << 16);
        u.z = f2bf(fB.x) | (f2bf(fB.y) << 16);
        u.w = f2bf(fB.z) | (f2bf(fB.w) << 16);
        w[i] = u;
        o4[(size_t)(r0 + i) * 512 + t] = u;
    }
    __syncthreads();
    // wave wid reduces rows 2wid,2wid+1; lane0 applies scalar tail inline
#pragma unroll
    for (int rr = 0; rr < 2; rr++) {
        int row = wid * 2 + rr;
        float v = 0.f;
#pragma unroll
        for (int k = 0; k < 8; k++) v += prt[row][lane + 64 * k];
#pragma unroll
        for (int o = 32; o; o >>= 1) v += __shfl_down(v, o, 64);
        if (lane == 0) {
            float q = 0.f;
#pragma unroll
            for (int k = 0; k < 4; k++) q += sigf(thqr[2 * k] * v + thqr[2 * k + 1]);
            float rmv = q * 0.25f;
            right_mask[r0 + row] = rmv;
            one_r[r0 + row] = 1.0f - rmv;
            y[r0 + row] = 0.f;
            rml[row] = rmv;
        }
    }
    __syncthreads();
    float cs[8], cm[8];
#pragma unroll
    for (int c = 0; c < 8; c++) { cs[c] = 0.f; cm[c] = -INFINITY; }
#pragma unroll
    for (int i = 0; i < RPB; i++) {
        float a[8];
        unpack8(w[i], a);
        float vi = rml[i];
#pragma unroll
        for (int c = 0; c < 8; c++) {
            cs[c] += a[c];
            cm[c] = fmaxf(cm[c], a[c] * vi);
        }
    }
    float4* q1 = reinterpret_cast<float4*>(p1 + (size_t)s * NCOLS + 8 * t);
    float4* q2 = reinterpret_cast<float4*>(p2 + (size_t)s * NCOLS + 8 * t);
    q1[0] = make_float4(cs[0], cs[1], cs[2], cs[3]);
    q1[1] = make_float4(cs[4], cs[5], cs[6], cs[7]);
    q2[0] = make_float4(cm[0], cm[1], cm[2], cm[3]);
    q2[1] = make_float4(cm[4], cm[5], cm[6], cm[7]);
}

// ============ fused: ro[i]=(A@b)*one_r  +  colmax partial p1 — ONE bf16 pass
__global__ __launch_bounds__(512) void k_ro_colmax(const unsigned* __restrict__ Abf,
                                                   const float* __restrict__ bvec,
                                                   const float* __restrict__ one_r,
                                                   float* __restrict__ ro,
                                                   float* __restrict__ p1) {
    __shared__ float prt[RPB][512];
    __shared__ float rol[RPB];
    int t = threadIdx.x, s = blockIdx.x, r0 = s * RPB;
    int wid = t >> 6, lane = t & 63;
    const uint4* a8 = reinterpret_cast<const uint4*>(Abf);
    const float4* b4 = reinterpret_cast<const float4*>(bvec);
    float4 bA = b4[2 * t];
    float4 bB = b4[2 * t + 1];
    float bb[8] = {bA.x, bA.y, bA.z, bA.w, bB.x, bB.y, bB.z, bB.w};
    uint4 w[RPB];
    // issue ALL row loads before any use: 16 loads in flight per thread
#pragma unroll
    for (int i = 0; i < RPB; i++) w[i] = a8[(size_t)(r0 + i) * 512 + t];
#pragma unroll
    for (int i = 0; i < RPB; i++) {
        float a[8];
        unpack8(w[i], a);
        float d = 0.f;
#pragma unroll
        for (int c = 0; c < 8; c++) d += a[c] * bb[c];
        prt[i][t] = d;
    }
    __syncthreads();
    // wave wid reduces rows 2wid,2wid+1; lane0 applies one_r inline
#pragma unroll
    for (int rr = 0; rr < 2; rr++) {
        int row = wid * 2 + rr;
        float v = 0.f;
#pragma unroll
        for (int k = 0; k < 8; k++) v += prt[row][lane + 64 * k];
#pragma unroll
        for (int o = 32; o; o >>= 1) v += __shfl_down(v, o, 64);
        if (lane == 0) {
            float rv = v * one_r[r0 + row];
            ro[r0 + row] = rv;
            rol[row] = rv;
        }
    }
    __syncthreads();
    float cm[8];
#pragma unroll
    for (int c = 0; c < 8; c++) cm[c] = -INFINITY;
#pragma unroll
    for (int i = 0; i < RPB; i++) {
        float a[8];
        unpack8(w[i], a);
        float vi = rol[i];
#pragma unroll
        for (int c = 0; c < 8; c++) cm[c] = fmaxf(cm[c], a[c] * vi);
    }
    float4* q1 = reinterpret_cast<float4*>(p1 + (size_t)s * NCOLS + 8 * t);
    q1[0] = make_float4(cm[0], cm[1], cm[2], cm[3]);
    q1[1] = make_float4(cm[4], cm[5], cm[6], cm[7]);
}

// ============ fused: row max-product + g_theta + y update + dual partials — ONE pass
// FINAL=1 additionally computes pred_dual[row] = y_final + right_mask + A@hw.
// g_theta parallelized: lanes 0-15 handle row 2wid, lanes 16-31 row 2wid+1.
template <int FINAL>
__global__ __launch_bounds__(512) void k_row_dual(
    const unsigned* __restrict__ Abf, const float* __restrict__ ro_t,
    const float* __restrict__ one_r, const float* __restrict__ ro,
    const float* __restrict__ tg, float* __restrict__ y, float* __restrict__ p1,
    float* __restrict__ p2, const float* __restrict__ hwv,
    const float* __restrict__ rm, float* __restrict__ out) {
    __shared__ float prt[RPB][512];
    __shared__ float prt2[FINAL ? RPB : 1][512];
    __shared__ float ydl[RPB];
    __shared__ float ydrol[RPB];
    int t = threadIdx.x, s = blockIdx.x, r0 = s * RPB;
    int wid = t >> 6, lane = t & 63;
    const uint4* a8 = reinterpret_cast<const uint4*>(Abf);
    const float4* v4 = reinterpret_cast<const float4*>(ro_t);
    float4 vA = v4[2 * t];
    float4 vB = v4[2 * t + 1];
    float vv[8] = {vA.x, vA.y, vA.z, vA.w, vB.x, vB.y, vB.z, vB.w};
    float hv[8];
    if (FINAL) {
        const float4* h4 = reinterpret_cast<const float4*>(hwv);
        float4 hA = h4[2 * t];
        float4 hB = h4[2 * t + 1];
        hv[0] = hA.x; hv[1] = hA.y; hv[2] = hA.z; hv[3] = hA.w;
        hv[4] = hB.x; hv[5] = hB.y; hv[6] = hB.z; hv[7] = hB.w;
    }
    uint4 w[RPB];
    // issue ALL row loads before any use
#pragma unroll
    for (int i = 0; i < RPB; i++) w[i] = a8[(size_t)(r0 + i) * 512 + t];
#pragma unroll
    for (int i = 0; i < RPB; i++) {
        float a[8];
        unpack8(w[i], a);
        float m = -INFINITY;
#pragma unroll
        for (int c = 0; c < 8; c++) m = fmaxf(m, a[c] * vv[c]);
        prt[i][t] = m;
        if (FINAL) {
            float d = 0.f;
#pragma unroll
            for (int c = 0; c < 8; c++) d += a[c] * hv[c];
            prt2[i][t] = d;
        }
    }
    __syncthreads();
    // wave wid: butterfly-reduce rows 2wid, 2wid+1 (result in ALL lanes),
    // then lanes 0-31 compute the 16 g_theta terms for the two rows in parallel.
    float m0, m1, d0 = 0.f, d1 = 0.f;
    {
        float v = -INFINITY;
#pragma unroll
        for (int k = 0; k < 8; k++) v = fmaxf(v, prt[wid * 2][lane + 64 * k]);
#pragma unroll
        for (int o = 32; o; o >>= 1) v = fmaxf(v, __shfl_xor(v, o, 64));
        m0 = v;
        v = -INFINITY;
#pragma unroll
        for (int k = 0; k < 8; k++) v = fmaxf(v, prt[wid * 2 + 1][lane + 64 * k]);
#pragma unroll
        for (int o = 32; o; o >>= 1) v = fmaxf(v, __shfl_xor(v, o, 64));
        m1 = v;
        if (FINAL) {
            float d = 0.f;
#pragma unroll
            for (int k = 0; k < 8; k++) d += prt2[wid * 2][lane + 64 * k];
#pragma unroll
            for (int o = 32; o; o >>= 1) d += __shfl_xor(d, o, 64);
            d0 = d;
            d = 0.f;
#pragma unroll
            for (int k = 0; k < 8; k++) d += prt2[wid * 2 + 1][lane + 64 * k];
#pragma unroll
            for (int o = 32; o; o >>= 1) d += __shfl_xor(d, o, 64);
            d1 = d;
        }
    }
    if (lane < 32) {
        int rr = lane >> 4;  // 0: row 2wid (lanes 0-15), 1: row 2wid+1 (lanes 16-31)
        int row = wid * 2 + rr;
        float m = rr ? m1 : m0;
        float oR = one_r[r0 + row];
        float roi = ro[r0 + row];
        float z = roi - m * oR * 0.5f;  // ro - ro_max/ALPHA
        int kk = lane & 15;
        float term = tg[3 * kk] * sigf(tg[3 * kk + 1] * z + tg[3 * kk + 2]);
        term += __shfl_down(term, 8, 16);
        term += __shfl_down(term, 4, 16);
        term += __shfl_down(term, 2, 16);
        term += __shfl_down(term, 1, 16);
        if (kk == 0) {
            float yd = term * oR;
            float yn = (y[r0 + row] + yd) * oR;
            y[r0 + row] = yn;
            ydl[row] = yd;
            ydrol[row] = yd / roi;
            if (FINAL) {
                float dd = rr ? d1 : d0;
                out[NCOLS + r0 + row] = yn + rm[r0 + row] + dd;  // pred_dual
            }
        }
    }
    __syncthreads();
    float s1[8], s2[8];
#pragma unroll
    for (int c = 0; c < 8; c++) { s1[c] = 0.f; s2[c] = 0.f; }
#pragma unroll
    for (int i = 0; i < RPB; i++) {
        float a[8];
        unpack8(w[i], a);
        float u = ydl[i];
        float q = ydrol[i];
#pragma unroll
        for (int c = 0; c < 8; c++) {
            s1[c] += a[c] * u;
            s2[c] += a[c] * q;
        }
    }
    float4* q1 = reinterpret_cast<float4*>(p1 + (size_t)s * NCOLS + 8 * t);
    float4* q2 = reinterpret_cast<float4*>(p2 + (size_t)s * NCOLS + 8 * t);
    q1[0] = make_float4(s1[0], s1[1], s1[2], s1[3]);
    q1[1] = make_float4(s1[4], s1[5], s1[6], s1[7]);
    q2[0] = make_float4(s2[0], s2[1], s2[2], s2[3]);
    q2[1] = make_float4(s2[4], s2[5], s2[6], s2[7]);
}

// ---------------- stage-2 reductions (parallel over splits) ----------------
// 512 blocks x 256 threads (2 blocks/CU); 8 columns/block; 32 groups x 8 splits.

__global__ __launch_bounds__(256) void k_left(const float* __restrict__ p1,
                                              const float* __restrict__ p2,
                                              const float* __restrict__ thql,
                                              const float* __restrict__ h,
                                              const float* __restrict__ fptr,
                                              float* __restrict__ one_l,
                                              float* __restrict__ hw,
                                              float* __restrict__ r,
                                              float* __restrict__ b,
                                              float* __restrict__ x) {
    __shared__ float smS[256];
    __shared__ float smM[256];
    int jl = threadIdx.x & 7;
    int g = threadIdx.x >> 3;  // 0..31
    int j = blockIdx.x * 8 + jl;
    float cs = 0.f, cm = -INFINITY;
#pragma unroll
    for (int t = 0; t < S2SP; t++) {
        int s = g * S2SP + t;
        cs += p1[(size_t)s * NCOLS + j];
        cm = fmaxf(cm, p2[(size_t)s * NCOLS + j]);
    }
    smS[threadIdx.x] = cs;
    smM[threadIdx.x] = cm;
    __syncthreads();
    if (g == 0) {
#pragma unroll
        for (int gg = 1; gg < 32; gg++) {
            cs += smS[gg * 8 + jl];
            cm = fmaxf(cm, smM[gg * 8 + jl]);
        }
        float q = 0.f;
#pragma unroll
        for (int k = 0; k < 4; k++) q += sigf(thql[2 * k] * cs + thql[2 * k + 1]);
        float c1 = q * 0.25f;
        float lm = fmaxf(c1, cm);
        one_l[j] = 1.0f - lm;
        hw[j] = h[j] * lm / cs;
        r[j] = fptr[0];
        b[j] = 1.0f;
        x[j] = 0.f;
    }
}

__global__ __launch_bounds__(256) void k_rot(const float* __restrict__ p,
                                             const float* __restrict__ one_l,
                                             float* __restrict__ ro_t) {
    __shared__ float smM[256];
    int jl = threadIdx.x & 7;
    int g = threadIdx.x >> 3;
    int j = blockIdx.x * 8 + jl;
    float m = -INFINITY;
#pragma unroll
    for (int t = 0; t < S2SP; t++) {
        int s = g * S2SP + t;
        m = fmaxf(m, p[(size_t)s * NCOLS + j]);
    }
    smM[threadIdx.x] = m;
    __syncthreads();
    if (g == 0) {
#pragma unroll
        for (int gg = 1; gg < 32; gg++) m = fmaxf(m, smM[gg * 8 + jl]);
        ro_t[j] = m * one_l[j];
    }
}

__global__ __launch_bounds__(256) void k_epilogue(const float* __restrict__ p1,
                                                  const float* __restrict__ p2,
                                                  const float* __restrict__ one_l,
                                                  const float* __restrict__ tb,
                                                  const float* __restrict__ fptr,
                                                  float* __restrict__ r,
                                                  float* __restrict__ b,
                                                  float* __restrict__ x,
                                                  float* __restrict__ out, int last) {
    __shared__ float smA[256];
    __shared__ float smB[256];
    int jl = threadIdx.x & 7;
    int g = threadIdx.x >> 3;
    int j = blockIdx.x * 8 + jl;
    float s1 = 0.f, s2 = 0.f;
#pragma unroll
    for (int t = 0; t < S2SP; t++) {
        int s = g * S2SP + t;
        s1 += p1[(size_t)s * NCOLS + j];
        s2 += p2[(size_t)s * NCOLS + j];
    }
    smA[threadIdx.x] = s1;
    smB[threadIdx.x] = s2;
    __syncthreads();
    if (g == 0) {
#pragma unroll
        for (int gg = 1; gg < 32; gg++) {
            s1 += smA[gg * 8 + jl];
            s2 += smB[gg * 8 + jl];
        }
        float oL = one_l[j];
        float rj = (r[j] - fmaxf(s1, 0.f)) * oL;
        float xj = (x[j] + b[j] * s2) * oL;
        float fv = fptr[0];
        float bb = 0.f;
#pragma unroll
        for (int k = 0; k < 16; k++) {
            float ak = tb[4 * k], bk = tb[4 * k + 1], ck = tb[4 * k + 2],
                  dk = tb[4 * k + 3];
            bb += ak * sigf(bk * rj + ck) * exp2f(-fmaxf(dk * (rj - fv), 0.f));
        }
        r[j] = rj;
        x[j] = xj;
        if (last) out[j] = xj;  // pred_primal
        b[j] = bb * oL;
    }
}

extern "C" void kernel_launch(void* const* d_in, const int* in_sizes, int n_in,
                              void* d_out, int out_size, void* d_ws, size_t ws_size,
                              hipStream_t stream) {
    const float* A = (const float*)d_in[0];
    const float* theta_g = (const float*)d_in[1];  // (5,16,3)
    const float* theta_b = (const float*)d_in[2];  // (5,16,4)
    const float* fptr = (const float*)d_in[3];     // scalar
    const float* h = (const float*)d_in[4];        // (N,)
    const float* thql = (const float*)d_in[5];     // (4,2)
    const float* thqr = (const float*)d_in[6];     // (4,2)
    float* out = (float*)d_out;  // [0:4096]=pred_primal(x), [4096:8192]=pred_dual

    // workspace layout (floats)
    float* ws = (float*)d_ws;
    float* right_mask = ws + 0 * 4096;
    float* one_r = ws + 1 * 4096;
    float* one_l = ws + 2 * 4096;
    float* hwv = ws + 3 * 4096;
    float* ro = ws + 4 * 4096;
    float* ro_t = ws + 5 * 4096;
    float* r = ws + 6 * 4096;
    float* b = ws + 7 * 4096;
    float* x = ws + 8 * 4096;
    float* y = ws + 9 * 4096;
    float* p1 = ws + 12 * 4096;
    float* p2 = p1 + (size_t)NSPLIT * NCOLS;
    unsigned* Abf = (unsigned*)(p2 + (size_t)NSPLIT * NCOLS);  // 32 MB bf16 copy

    // preamble: ONE pass over fp32 A (convert + rowsum/right_mask + col partials)
    k_pre_fused<<<NSPLIT, 512, 0, stream>>>(A, Abf, thqr, right_mask, one_r, y, p1, p2);
    k_left<<<512, 256, 0, stream>>>(p1, p2, thql, h, fptr, one_l, hwv, r, b, x);

    // layers: last k_row_dual also emits pred_dual; last epilogue emits pred_primal
    for (int l = 0; l < NLAYERS; l++) {
        k_ro_colmax<<<NSPLIT, 512, 0, stream>>>(Abf, b, one_r, ro, p1);
        k_rot<<<512, 256, 0, stream>>>(p1, one_l, ro_t);
        if (l < NLAYERS - 1)
            k_row_dual<0><<<NSPLIT, 512, 0, stream>>>(Abf, ro_t, one_r, ro,
                                                      theta_g + l * 48, y, p1, p2, hwv,
                                                      right_mask, out);
        else
            k_row_dual<1><<<NSPLIT, 512, 0, stream>>>(Abf, ro_t, one_r, ro,
                                                      theta_g + l * 48, y, p1, p2, hwv,
                                                      right_mask, out);
        k_epilogue<<<512, 256, 0, stream>>>(p1, p2, one_l, theta_b + l * 64, fptr, r, b,
                                            x, out, l == NLAYERS - 1);
    }
}

// Round 10
// 169.823 us; speedup vs baseline: 1.1534x; 1.1534x over previous
//
#include <hip/hip_runtime.h>
#include <math.h>

#define NCOLS 4096
#define MROWS 4096
#define NLAYERS 5
#define RPB 16                // rows per fused block
#define NSPLIT (MROWS / RPB)  // 256 column-partial splits
// stage-2: 256 blocks x 256 threads; 16 cols/block (4 float4 slots);
// thread (slot=t&3, g=t>>2) gathers 4 splits; 6-step LDS tree combines 64 groups.

__device__ __forceinline__ float sigf(float x) { return 1.0f / (1.0f + expf(-x)); }

// bf16 (packed in 32-bit words) -> float, exact
__device__ __forceinline__ float lo16(unsigned w) { return __uint_as_float(w << 16); }
__device__ __forceinline__ float hi16(unsigned w) { return __uint_as_float(w & 0xFFFF0000u); }

// float -> bf16 bits, round-to-nearest-even (A has no NaN/Inf)
__device__ __forceinline__ unsigned f2bf(float f) {
    unsigned u = __float_as_uint(f);
    return (u + 0x7FFFu + ((u >> 16) & 1u)) >> 16;
}

__device__ __forceinline__ void unpack8(uint4 w, float* a) {
    a[0] = lo16(w.x); a[1] = hi16(w.x); a[2] = lo16(w.y); a[3] = hi16(w.y);
    a[4] = lo16(w.z); a[5] = hi16(w.z); a[6] = lo16(w.w); a[7] = hi16(w.w);
}

__device__ __forceinline__ float4 f4add(float4 a, float4 b) {
    return make_float4(a.x + b.x, a.y + b.y, a.z + b.z, a.w + b.w);
}
__device__ __forceinline__ float4 f4max(float4 a, float4 b) {
    return make_float4(fmaxf(a.x, b.x), fmaxf(a.y, b.y), fmaxf(a.z, b.z),
                       fmaxf(a.w, b.w));
}

// ============ fused preamble: fp32 read, bf16 convert+store, rowsum->right_mask,
// ============ colsum partial p1, colmax(rm) partial p2 — ONE pass over fp32 A
__global__ __launch_bounds__(512) void k_pre_fused(
    const float* __restrict__ A, unsigned* __restrict__ Abf,
    const float* __restrict__ thqr, float* __restrict__ right_mask,
    float* __restrict__ one_r, float* __restrict__ y, float* __restrict__ p1,
    float* __restrict__ p2) {
    __shared__ float prt[RPB][512];
    __shared__ float rml[RPB];
    int t = threadIdx.x, s = blockIdx.x, r0 = s * RPB;
    int wid = t >> 6, lane = t & 63;
    const float4* a4 = reinterpret_cast<const float4*>(A);
    uint4* o4 = reinterpret_cast<uint4*>(Abf);
    uint4 w[RPB];
#pragma unroll
    for (int i = 0; i < RPB; i++) {
        size_t base = (size_t)(r0 + i) * 1024 + 2 * t;
        float4 fA = a4[base];
        float4 fB = a4[base + 1];
        prt[i][t] = ((fA.x + fA.y) + (fA.z + fA.w)) + ((fB.x + fB.y) + (fB.z + fB.w));
        uint4 u;
        u.x = f2bf(fA.x) | (f2bf(fA.y) << 16);
        u.y = f2bf(fA.z) | (f2bf(fA.w) << 16);
        u.z = f2bf(fB.x) | (f2bf(fB.y) << 16);
        u.w = f2bf(fB.z) | (f2bf(fB.w) << 16);
        w[i] = u;
        o4[(size_t)(r0 + i) * 512 + t] = u;
    }
    __syncthreads();
    // wave wid reduces rows 2wid,2wid+1; lane0 applies scalar tail inline
#pragma unroll
    for (int rr = 0; rr < 2; rr++) {
        int row = wid * 2 + rr;
        float v = 0.f;
#pragma unroll
        for (int k = 0; k < 8; k++) v += prt[row][lane + 64 * k];
#pragma unroll
        for (int o = 32; o; o >>= 1) v += __shfl_down(v, o, 64);
        if (lane == 0) {
            float q = 0.f;
#pragma unroll
            for (int k = 0; k < 4; k++) q += sigf(thqr[2 * k] * v + thqr[2 * k + 1]);
            float rmv = q * 0.25f;
            right_mask[r0 + row] = rmv;
            one_r[r0 + row] = 1.0f - rmv;
            y[r0 + row] = 0.f;
            rml[row] = rmv;
        }
    }
    __syncthreads();
    float cs[8], cm[8];
#pragma unroll
    for (int c = 0; c < 8; c++) { cs[c] = 0.f; cm[c] = -INFINITY; }
#pragma unroll
    for (int i = 0; i < RPB; i++) {
        float a[8];
        unpack8(w[i], a);
        float vi = rml[i];
#pragma unroll
        for (int c = 0; c < 8; c++) {
            cs[c] += a[c];
            cm[c] = fmaxf(cm[c], a[c] * vi);
        }
    }
    float4* q1 = reinterpret_cast<float4*>(p1 + (size_t)s * NCOLS + 8 * t);
    float4* q2 = reinterpret_cast<float4*>(p2 + (size_t)s * NCOLS + 8 * t);
    q1[0] = make_float4(cs[0], cs[1], cs[2], cs[3]);
    q1[1] = make_float4(cs[4], cs[5], cs[6], cs[7]);
    q2[0] = make_float4(cm[0], cm[1], cm[2], cm[3]);
    q2[1] = make_float4(cm[4], cm[5], cm[6], cm[7]);
}

// ============ fused: ro[i]=(A@b)*one_r  +  colmax partial p1 — ONE bf16 pass
__global__ __launch_bounds__(512) void k_ro_colmax(const unsigned* __restrict__ Abf,
                                                   const float* __restrict__ bvec,
                                                   const float* __restrict__ one_r,
                                                   float* __restrict__ ro,
                                                   float* __restrict__ p1) {
    __shared__ float prt[RPB][512];
    __shared__ float rol[RPB];
    int t = threadIdx.x, s = blockIdx.x, r0 = s * RPB;
    int wid = t >> 6, lane = t & 63;
    const uint4* a8 = reinterpret_cast<const uint4*>(Abf);
    const float4* b4 = reinterpret_cast<const float4*>(bvec);
    float4 bA = b4[2 * t];
    float4 bB = b4[2 * t + 1];
    float bb[8] = {bA.x, bA.y, bA.z, bA.w, bB.x, bB.y, bB.z, bB.w};
    uint4 w[RPB];
#pragma unroll
    for (int i = 0; i < RPB; i++) {
        w[i] = a8[(size_t)(r0 + i) * 512 + t];
        float a[8];
        unpack8(w[i], a);
        float d = 0.f;
#pragma unroll
        for (int c = 0; c < 8; c++) d += a[c] * bb[c];
        prt[i][t] = d;
    }
    __syncthreads();
    // wave wid reduces rows 2wid,2wid+1; lane0 applies one_r inline
#pragma unroll
    for (int rr = 0; rr < 2; rr++) {
        int row = wid * 2 + rr;
        float v = 0.f;
#pragma unroll
        for (int k = 0; k < 8; k++) v += prt[row][lane + 64 * k];
#pragma unroll
        for (int o = 32; o; o >>= 1) v += __shfl_down(v, o, 64);
        if (lane == 0) {
            float rv = v * one_r[r0 + row];
            ro[r0 + row] = rv;
            rol[row] = rv;
        }
    }
    __syncthreads();
    float cm[8];
#pragma unroll
    for (int c = 0; c < 8; c++) cm[c] = -INFINITY;
#pragma unroll
    for (int i = 0; i < RPB; i++) {
        float a[8];
        unpack8(w[i], a);
        float vi = rol[i];
#pragma unroll
        for (int c = 0; c < 8; c++) cm[c] = fmaxf(cm[c], a[c] * vi);
    }
    float4* q1 = reinterpret_cast<float4*>(p1 + (size_t)s * NCOLS + 8 * t);
    q1[0] = make_float4(cm[0], cm[1], cm[2], cm[3]);
    q1[1] = make_float4(cm[4], cm[5], cm[6], cm[7]);
}

// ============ fused: row max-product + g_theta + y update + dual partials — ONE pass
// FINAL=1 additionally computes pred_dual[row] = y_final + right_mask + A@hw.
// g_theta parallelized: lanes 0-15 handle row 2wid, lanes 16-31 row 2wid+1.
template <int FINAL>
__global__ __launch_bounds__(512) void k_row_dual(
    const unsigned* __restrict__ Abf, const float* __restrict__ ro_t,
    const float* __restrict__ one_r, const float* __restrict__ ro,
    const float* __restrict__ tg, float* __restrict__ y, float* __restrict__ p1,
    float* __restrict__ p2, const float* __restrict__ hwv,
    const float* __restrict__ rm, float* __restrict__ out) {
    __shared__ float prt[RPB][512];
    __shared__ float prt2[FINAL ? RPB : 1][512];
    __shared__ float ydl[RPB];
    __shared__ float ydrol[RPB];
    int t = threadIdx.x, s = blockIdx.x, r0 = s * RPB;
    int wid = t >> 6, lane = t & 63;
    const uint4* a8 = reinterpret_cast<const uint4*>(Abf);
    const float4* v4 = reinterpret_cast<const float4*>(ro_t);
    float4 vA = v4[2 * t];
    float4 vB = v4[2 * t + 1];
    float vv[8] = {vA.x, vA.y, vA.z, vA.w, vB.x, vB.y, vB.z, vB.w};
    float hv[8];
    if (FINAL) {
        const float4* h4 = reinterpret_cast<const float4*>(hwv);
        float4 hA = h4[2 * t];
        float4 hB = h4[2 * t + 1];
        hv[0] = hA.x; hv[1] = hA.y; hv[2] = hA.z; hv[3] = hA.w;
        hv[4] = hB.x; hv[5] = hB.y; hv[6] = hB.z; hv[7] = hB.w;
    }
    uint4 w[RPB];
#pragma unroll
    for (int i = 0; i < RPB; i++) {
        w[i] = a8[(size_t)(r0 + i) * 512 + t];
        float a[8];
        unpack8(w[i], a);
        float m = -INFINITY;
#pragma unroll
        for (int c = 0; c < 8; c++) m = fmaxf(m, a[c] * vv[c]);
        prt[i][t] = m;
        if (FINAL) {
            float d = 0.f;
#pragma unroll
            for (int c = 0; c < 8; c++) d += a[c] * hv[c];
            prt2[i][t] = d;
        }
    }
    __syncthreads();
    // wave wid: butterfly-reduce rows 2wid, 2wid+1 (result in ALL lanes),
    // then lanes 0-31 compute the 16 g_theta terms for the two rows in parallel.
    float m0, m1, d0 = 0.f, d1 = 0.f;
    {
        float v = -INFINITY;
#pragma unroll
        for (int k = 0; k < 8; k++) v = fmaxf(v, prt[wid * 2][lane + 64 * k]);
#pragma unroll
        for (int o = 32; o; o >>= 1) v = fmaxf(v, __shfl_xor(v, o, 64));
        m0 = v;
        v = -INFINITY;
#pragma unroll
        for (int k = 0; k < 8; k++) v = fmaxf(v, prt[wid * 2 + 1][lane + 64 * k]);
#pragma unroll
        for (int o = 32; o; o >>= 1) v = fmaxf(v, __shfl_xor(v, o, 64));
        m1 = v;
        if (FINAL) {
            float d = 0.f;
#pragma unroll
            for (int k = 0; k < 8; k++) d += prt2[wid * 2][lane + 64 * k];
#pragma unroll
            for (int o = 32; o; o >>= 1) d += __shfl_xor(d, o, 64);
            d0 = d;
            d = 0.f;
#pragma unroll
            for (int k = 0; k < 8; k++) d += prt2[wid * 2 + 1][lane + 64 * k];
#pragma unroll
            for (int o = 32; o; o >>= 1) d += __shfl_xor(d, o, 64);
            d1 = d;
        }
    }
    if (lane < 32) {
        int rr = lane >> 4;  // 0: row 2wid (lanes 0-15), 1: row 2wid+1 (lanes 16-31)
        int row = wid * 2 + rr;
        float m = rr ? m1 : m0;
        float oR = one_r[r0 + row];
        float roi = ro[r0 + row];
        float z = roi - m * oR * 0.5f;  // ro - ro_max/ALPHA
        int kk = lane & 15;
        float term = tg[3 * kk] * sigf(tg[3 * kk + 1] * z + tg[3 * kk + 2]);
        term += __shfl_down(term, 8, 16);
        term += __shfl_down(term, 4, 16);
        term += __shfl_down(term, 2, 16);
        term += __shfl_down(term, 1, 16);
        if (kk == 0) {
            float yd = term * oR;
            float yn = (y[r0 + row] + yd) * oR;
            y[r0 + row] = yn;
            ydl[row] = yd;
            ydrol[row] = yd / roi;
            if (FINAL) {
                float dd = rr ? d1 : d0;
                out[NCOLS + r0 + row] = yn + rm[r0 + row] + dd;  // pred_dual
            }
        }
    }
    __syncthreads();
    float s1[8], s2[8];
#pragma unroll
    for (int c = 0; c < 8; c++) { s1[c] = 0.f; s2[c] = 0.f; }
#pragma unroll
    for (int i = 0; i < RPB; i++) {
        float a[8];
        unpack8(w[i], a);
        float u = ydl[i];
        float q = ydrol[i];
#pragma unroll
        for (int c = 0; c < 8; c++) {
            s1[c] += a[c] * u;
            s2[c] += a[c] * q;
        }
    }
    float4* q1 = reinterpret_cast<float4*>(p1 + (size_t)s * NCOLS + 8 * t);
    float4* q2 = reinterpret_cast<float4*>(p2 + (size_t)s * NCOLS + 8 * t);
    q1[0] = make_float4(s1[0], s1[1], s1[2], s1[3]);
    q1[1] = make_float4(s1[4], s1[5], s1[6], s1[7]);
    q2[0] = make_float4(s2[0], s2[1], s2[2], s2[3]);
    q2[1] = make_float4(s2[4], s2[5], s2[6], s2[7]);
}

// ---------------- stage-2 reductions (parallel over splits) ----------------
// 256 blocks x 256 threads; 16 cols/block as 4 float4 slots.
// Thread (slot=t&3, g=t>>2): 4-deep float4 gather; 6-step LDS tree over 64 groups.
// After the tree, sm[0..3] = the 16 column results in order.

__global__ __launch_bounds__(256) void k_left(const float* __restrict__ p1,
                                              const float* __restrict__ p2,
                                              const float* __restrict__ thql,
                                              const float* __restrict__ h,
                                              const float* __restrict__ fptr,
                                              float* __restrict__ one_l,
                                              float* __restrict__ hw,
                                              float* __restrict__ r,
                                              float* __restrict__ b,
                                              float* __restrict__ x) {
    __shared__ float4 sm1[256];
    __shared__ float4 sm2[256];
    int t = threadIdx.x;
    int slot = t & 3, g = t >> 2;
    const float4* q1 = reinterpret_cast<const float4*>(p1);
    const float4* q2 = reinterpret_cast<const float4*>(p2);
    int base = blockIdx.x * 4 + slot;
    float4 cs = make_float4(0.f, 0.f, 0.f, 0.f);
    float4 cm = make_float4(-INFINITY, -INFINITY, -INFINITY, -INFINITY);
#pragma unroll
    for (int k = 0; k < 4; k++) {
        int sp = g * 4 + k;
        cs = f4add(cs, q1[(size_t)sp * 1024 + base]);
        cm = f4max(cm, q2[(size_t)sp * 1024 + base]);
    }
    sm1[t] = cs;
    sm2[t] = cm;
    __syncthreads();
#pragma unroll
    for (int st = 32; st >= 1; st >>= 1) {
        if (g < st) {
            sm1[t] = f4add(sm1[t], sm1[t + st * 4]);
            sm2[t] = f4max(sm2[t], sm2[t + st * 4]);
        }
        __syncthreads();
    }
    if (t < 16) {
        float csv = reinterpret_cast<const float*>(sm1)[t];
        float cmv = reinterpret_cast<const float*>(sm2)[t];
        int j = blockIdx.x * 16 + t;
        float q = 0.f;
#pragma unroll
        for (int k = 0; k < 4; k++) q += sigf(thql[2 * k] * csv + thql[2 * k + 1]);
        float lm = fmaxf(q * 0.25f, cmv);
        one_l[j] = 1.0f - lm;
        hw[j] = h[j] * lm / csv;
        r[j] = fptr[0];
        b[j] = 1.0f;
        x[j] = 0.f;
    }
}

__global__ __launch_bounds__(256) void k_rot(const float* __restrict__ p,
                                             const float* __restrict__ one_l,
                                             float* __restrict__ ro_t) {
    __shared__ float4 sm1[256];
    int t = threadIdx.x;
    int slot = t & 3, g = t >> 2;
    const float4* q1 = reinterpret_cast<const float4*>(p);
    int base = blockIdx.x * 4 + slot;
    float4 cm = make_float4(-INFINITY, -INFINITY, -INFINITY, -INFINITY);
#pragma unroll
    for (int k = 0; k < 4; k++) {
        int sp = g * 4 + k;
        cm = f4max(cm, q1[(size_t)sp * 1024 + base]);
    }
    sm1[t] = cm;
    __syncthreads();
#pragma unroll
    for (int st = 32; st >= 1; st >>= 1) {
        if (g < st) sm1[t] = f4max(sm1[t], sm1[t + st * 4]);
        __syncthreads();
    }
    if (t < 16) {
        int j = blockIdx.x * 16 + t;
        ro_t[j] = reinterpret_cast<const float*>(sm1)[t] * one_l[j];
    }
}

__global__ __launch_bounds__(256) void k_epilogue(const float* __restrict__ p1,
                                                  const float* __restrict__ p2,
                                                  const float* __restrict__ one_l,
                                                  const float* __restrict__ tb,
                                                  const float* __restrict__ fptr,
                                                  float* __restrict__ r,
                                                  float* __restrict__ b,
                                                  float* __restrict__ x,
                                                  float* __restrict__ out, int last) {
    __shared__ float4 sm1[256];
    __shared__ float4 sm2[256];
    int t = threadIdx.x;
    int slot = t & 3, g = t >> 2;
    const float4* q1 = reinterpret_cast<const float4*>(p1);
    const float4* q2 = reinterpret_cast<const float4*>(p2);
    int base = blockIdx.x * 4 + slot;
    float4 s1 = make_float4(0.f, 0.f, 0.f, 0.f);
    float4 s2 = make_float4(0.f, 0.f, 0.f, 0.f);
#pragma unroll
    for (int k = 0; k < 4; k++) {
        int sp = g * 4 + k;
        s1 = f4add(s1, q1[(size_t)sp * 1024 + base]);
        s2 = f4add(s2, q2[(size_t)sp * 1024 + base]);
    }
    sm1[t] = s1;
    sm2[t] = s2;
    __syncthreads();
#pragma unroll
    for (int st = 32; st >= 1; st >>= 1) {
        if (g < st) {
            sm1[t] = f4add(sm1[t], sm1[t + st * 4]);
            sm2[t] = f4add(sm2[t], sm2[t + st * 4]);
        }
        __syncthreads();
    }
    if (t < 16) {
        float s1v = reinterpret_cast<const float*>(sm1)[t];
        float s2v = reinterpret_cast<const float*>(sm2)[t];
        int j = blockIdx.x * 16 + t;
        float oL = one_l[j];
        float rj = (r[j] - fmaxf(s1v, 0.f)) * oL;
        float xj = (x[j] + b[j] * s2v) * oL;
        float fv = fptr[0];
        float bb = 0.f;
#pragma unroll
        for (int k = 0; k < 16; k++) {
            float ak = tb[4 * k], bk = tb[4 * k + 1], ck = tb[4 * k + 2],
                  dk = tb[4 * k + 3];
            bb += ak * sigf(bk * rj + ck) * exp2f(-fmaxf(dk * (rj - fv), 0.f));
        }
        r[j] = rj;
        x[j] = xj;
        if (last) out[j] = xj;  // pred_primal
        b[j] = bb * oL;
    }
}

extern "C" void kernel_launch(void* const* d_in, const int* in_sizes, int n_in,
                              void* d_out, int out_size, void* d_ws, size_t ws_size,
                              hipStream_t stream) {
    const float* A = (const float*)d_in[0];
    const float* theta_g = (const float*)d_in[1];  // (5,16,3)
    const float* theta_b = (const float*)d_in[2];  // (5,16,4)
    const float* fptr = (const float*)d_in[3];     // scalar
    const float* h = (const float*)d_in[4];        // (N,)
    const float* thql = (const float*)d_in[5];     // (4,2)
    const float* thqr = (const float*)d_in[6];     // (4,2)
    float* out = (float*)d_out;  // [0:4096]=pred_primal(x), [4096:8192]=pred_dual

    // workspace layout (floats)
    float* ws = (float*)d_ws;
    float* right_mask = ws + 0 * 4096;
    float* one_r = ws + 1 * 4096;
    float* one_l = ws + 2 * 4096;
    float* hwv = ws + 3 * 4096;
    float* ro = ws + 4 * 4096;
    float* ro_t = ws + 5 * 4096;
    float* r = ws + 6 * 4096;
    float* b = ws + 7 * 4096;
    float* x = ws + 8 * 4096;
    float* y = ws + 9 * 4096;
    float* p1 = ws + 12 * 4096;
    float* p2 = p1 + (size_t)NSPLIT * NCOLS;
    unsigned* Abf = (unsigned*)(p2 + (size_t)NSPLIT * NCOLS);  // 32 MB bf16 copy

    // preamble: ONE pass over fp32 A (convert + rowsum/right_mask + col partials)
    k_pre_fused<<<NSPLIT, 512, 0, stream>>>(A, Abf, thqr, right_mask, one_r, y, p1, p2);
    k_left<<<256, 256, 0, stream>>>(p1, p2, thql, h, fptr, one_l, hwv, r, b, x);

    // layers: last k_row_dual also emits pred_dual; last epilogue emits pred_primal
    for (int l = 0; l < NLAYERS; l++) {
        k_ro_colmax<<<NSPLIT, 512, 0, stream>>>(Abf, b, one_r, ro, p1);
        k_rot<<<256, 256, 0, stream>>>(p1, one_l, ro_t);
        if (l < NLAYERS - 1)
            k_row_dual<0><<<NSPLIT, 512, 0, stream>>>(Abf, ro_t, one_r, ro,
                                                      theta_g + l * 48, y, p1, p2, hwv,
                                                      right_mask, out);
        else
            k_row_dual<1><<<NSPLIT, 512, 0, stream>>>(Abf, ro_t, one_r, ro,
                                                      theta_g + l * 48, y, p1, p2, hwv,
                                                      right_mask, out);
        k_epilogue<<<256, 256, 0, stream>>>(p1, p2, one_l, theta_b + l * 64, fptr, r, b,
                                            x, out, l == NLAYERS - 1);
    }
}

// Round 11
// 164.308 us; speedup vs baseline: 1.1921x; 1.0336x over previous
//
#include <hip/hip_runtime.h>
#include <math.h>

#define NCOLS 4096
#define MROWS 4096
#define NLAYERS 5
#define RPB 16                // rows per fused block
#define NSPLIT (MROWS / RPB)  // 256 column-partial splits
// stage-2: 256 blocks x 256 threads; 16 cols/block; 16 groups x 16 splits
#define S2SP (NSPLIT / 16)

__device__ __forceinline__ float sigf(float x) { return 1.0f / (1.0f + expf(-x)); }

// bf16 (packed in 32-bit words) -> float, exact
__device__ __forceinline__ float lo16(unsigned w) { return __uint_as_float(w << 16); }
__device__ __forceinline__ float hi16(unsigned w) { return __uint_as_float(w & 0xFFFF0000u); }

// float -> bf16 bits, round-to-nearest-even (A has no NaN/Inf)
__device__ __forceinline__ unsigned f2bf(float f) {
    unsigned u = __float_as_uint(f);
    return (u + 0x7FFFu + ((u >> 16) & 1u)) >> 16;
}

__device__ __forceinline__ void unpack8(uint4 w, float* a) {
    a[0] = lo16(w.x); a[1] = hi16(w.x); a[2] = lo16(w.y); a[3] = hi16(w.y);
    a[4] = lo16(w.z); a[5] = hi16(w.z); a[6] = lo16(w.w); a[7] = hi16(w.w);
}

// ============ fused preamble: fp32 read, bf16 convert+store, rowsum->right_mask,
// ============ colsum partial p1, colmax(rm) partial p2 — ONE pass over fp32 A
__global__ __launch_bounds__(512) void k_pre_fused(
    const float* __restrict__ A, unsigned* __restrict__ Abf,
    const float* __restrict__ thqr, float* __restrict__ right_mask,
    float* __restrict__ one_r, float* __restrict__ y, float* __restrict__ p1,
    float* __restrict__ p2) {
    __shared__ float prt[RPB][512];
    __shared__ float rml[RPB];
    int t = threadIdx.x, s = blockIdx.x, r0 = s * RPB;
    int wid = t >> 6, lane = t & 63;
    const float4* a4 = reinterpret_cast<const float4*>(A);
    uint4* o4 = reinterpret_cast<uint4*>(Abf);
    uint4 w[RPB];
#pragma unroll
    for (int i = 0; i < RPB; i++) {
        size_t base = (size_t)(r0 + i) * 1024 + 2 * t;
        float4 fA = a4[base];
        float4 fB = a4[base + 1];
        prt[i][t] = ((fA.x + fA.y) + (fA.z + fA.w)) + ((fB.x + fB.y) + (fB.z + fB.w));
        uint4 u;
        u.x = f2bf(fA.x) | (f2bf(fA.y) << 16);
        u.y = f2bf(fA.z) | (f2bf(fA.w) << 16);
        u.z = f2bf(fB.x) | (f2bf(fB.y) << 16);
        u.w = f2bf(fB.z) | (f2bf(fB.w) << 16);
        w[i] = u;
        o4[(size_t)(r0 + i) * 512 + t] = u;
    }
    __syncthreads();
    // wave wid reduces rows 2wid,2wid+1; lane0 applies scalar tail inline
#pragma unroll
    for (int rr = 0; rr < 2; rr++) {
        int row = wid * 2 + rr;
        float v = 0.f;
#pragma unroll
        for (int k = 0; k < 8; k++) v += prt[row][lane + 64 * k];
#pragma unroll
        for (int o = 32; o; o >>= 1) v += __shfl_down(v, o, 64);
        if (lane == 0) {
            float q = 0.f;
#pragma unroll
            for (int k = 0; k < 4; k++) q += sigf(thqr[2 * k] * v + thqr[2 * k + 1]);
            float rmv = q * 0.25f;
            right_mask[r0 + row] = rmv;
            one_r[r0 + row] = 1.0f - rmv;
            y[r0 + row] = 0.f;
            rml[row] = rmv;
        }
    }
    __syncthreads();
    float cs[8], cm[8];
#pragma unroll
    for (int c = 0; c < 8; c++) { cs[c] = 0.f; cm[c] = -INFINITY; }
#pragma unroll
    for (int i = 0; i < RPB; i++) {
        float a[8];
        unpack8(w[i], a);
        float vi = rml[i];
#pragma unroll
        for (int c = 0; c < 8; c++) {
            cs[c] += a[c];
            cm[c] = fmaxf(cm[c], a[c] * vi);
        }
    }
    float4* q1 = reinterpret_cast<float4*>(p1 + (size_t)s * NCOLS + 8 * t);
    float4* q2 = reinterpret_cast<float4*>(p2 + (size_t)s * NCOLS + 8 * t);
    q1[0] = make_float4(cs[0], cs[1], cs[2], cs[3]);
    q1[1] = make_float4(cs[4], cs[5], cs[6], cs[7]);
    q2[0] = make_float4(cm[0], cm[1], cm[2], cm[3]);
    q2[1] = make_float4(cm[4], cm[5], cm[6], cm[7]);
}

// ============ fused: ro[i]=(A@b)*one_r  +  colmax partial p1 — ONE bf16 pass
__global__ __launch_bounds__(512) void k_ro_colmax(const unsigned* __restrict__ Abf,
                                                   const float* __restrict__ bvec,
                                                   const float* __restrict__ one_r,
                                                   float* __restrict__ ro,
                                                   float* __restrict__ p1) {
    __shared__ float prt[RPB][512];
    __shared__ float rol[RPB];
    int t = threadIdx.x, s = blockIdx.x, r0 = s * RPB;
    int wid = t >> 6, lane = t & 63;
    const uint4* a8 = reinterpret_cast<const uint4*>(Abf);
    const float4* b4 = reinterpret_cast<const float4*>(bvec);
    float4 bA = b4[2 * t];
    float4 bB = b4[2 * t + 1];
    float bb[8] = {bA.x, bA.y, bA.z, bA.w, bB.x, bB.y, bB.z, bB.w};
    uint4 w[RPB];
#pragma unroll
    for (int i = 0; i < RPB; i++) {
        w[i] = a8[(size_t)(r0 + i) * 512 + t];
        float a[8];
        unpack8(w[i], a);
        float d = 0.f;
#pragma unroll
        for (int c = 0; c < 8; c++) d += a[c] * bb[c];
        prt[i][t] = d;
    }
    __syncthreads();
    // wave wid reduces rows 2wid,2wid+1; lane0 applies one_r inline
#pragma unroll
    for (int rr = 0; rr < 2; rr++) {
        int row = wid * 2 + rr;
        float v = 0.f;
#pragma unroll
        for (int k = 0; k < 8; k++) v += prt[row][lane + 64 * k];
#pragma unroll
        for (int o = 32; o; o >>= 1) v += __shfl_down(v, o, 64);
        if (lane == 0) {
            float rv = v * one_r[r0 + row];
            ro[r0 + row] = rv;
            rol[row] = rv;
        }
    }
    __syncthreads();
    float cm[8];
#pragma unroll
    for (int c = 0; c < 8; c++) cm[c] = -INFINITY;
#pragma unroll
    for (int i = 0; i < RPB; i++) {
        float a[8];
        unpack8(w[i], a);
        float vi = rol[i];
#pragma unroll
        for (int c = 0; c < 8; c++) cm[c] = fmaxf(cm[c], a[c] * vi);
    }
    float4* q1 = reinterpret_cast<float4*>(p1 + (size_t)s * NCOLS + 8 * t);
    q1[0] = make_float4(cm[0], cm[1], cm[2], cm[3]);
    q1[1] = make_float4(cm[4], cm[5], cm[6], cm[7]);
}

// ============ fused: row max-product + g_theta + y update + dual partials — ONE pass
// FINAL=1 additionally computes pred_dual[row] = y_final + right_mask + A@hw.
// g_theta parallelized: lanes 0-15 handle row 2wid, lanes 16-31 row 2wid+1.
template <int FINAL>
__global__ __launch_bounds__(512) void k_row_dual(
    const unsigned* __restrict__ Abf, const float* __restrict__ ro_t,
    const float* __restrict__ one_r, const float* __restrict__ ro,
    const float* __restrict__ tg, float* __restrict__ y, float* __restrict__ p1,
    float* __restrict__ p2, const float* __restrict__ hwv,
    const float* __restrict__ rm, float* __restrict__ out) {
    __shared__ float prt[RPB][512];
    __shared__ float prt2[FINAL ? RPB : 1][512];
    __shared__ float ydl[RPB];
    __shared__ float ydrol[RPB];
    int t = threadIdx.x, s = blockIdx.x, r0 = s * RPB;
    int wid = t >> 6, lane = t & 63;
    const uint4* a8 = reinterpret_cast<const uint4*>(Abf);
    const float4* v4 = reinterpret_cast<const float4*>(ro_t);
    float4 vA = v4[2 * t];
    float4 vB = v4[2 * t + 1];
    float vv[8] = {vA.x, vA.y, vA.z, vA.w, vB.x, vB.y, vB.z, vB.w};
    float hv[8];
    if (FINAL) {
        const float4* h4 = reinterpret_cast<const float4*>(hwv);
        float4 hA = h4[2 * t];
        float4 hB = h4[2 * t + 1];
        hv[0] = hA.x; hv[1] = hA.y; hv[2] = hA.z; hv[3] = hA.w;
        hv[4] = hB.x; hv[5] = hB.y; hv[6] = hB.z; hv[7] = hB.w;
    }
    uint4 w[RPB];
#pragma unroll
    for (int i = 0; i < RPB; i++) {
        w[i] = a8[(size_t)(r0 + i) * 512 + t];
        float a[8];
        unpack8(w[i], a);
        float m = -INFINITY;
#pragma unroll
        for (int c = 0; c < 8; c++) m = fmaxf(m, a[c] * vv[c]);
        prt[i][t] = m;
        if (FINAL) {
            float d = 0.f;
#pragma unroll
            for (int c = 0; c < 8; c++) d += a[c] * hv[c];
            prt2[i][t] = d;
        }
    }
    __syncthreads();
    // wave wid: butterfly-reduce rows 2wid, 2wid+1 (result in ALL lanes),
    // then lanes 0-31 compute the 16 g_theta terms for the two rows in parallel.
    float m0, m1, d0 = 0.f, d1 = 0.f;
    {
        float v = -INFINITY;
#pragma unroll
        for (int k = 0; k < 8; k++) v = fmaxf(v, prt[wid * 2][lane + 64 * k]);
#pragma unroll
        for (int o = 32; o; o >>= 1) v = fmaxf(v, __shfl_xor(v, o, 64));
        m0 = v;
        v = -INFINITY;
#pragma unroll
        for (int k = 0; k < 8; k++) v = fmaxf(v, prt[wid * 2 + 1][lane + 64 * k]);
#pragma unroll
        for (int o = 32; o; o >>= 1) v = fmaxf(v, __shfl_xor(v, o, 64));
        m1 = v;
        if (FINAL) {
            float d = 0.f;
#pragma unroll
            for (int k = 0; k < 8; k++) d += prt2[wid * 2][lane + 64 * k];
#pragma unroll
            for (int o = 32; o; o >>= 1) d += __shfl_xor(d, o, 64);
            d0 = d;
            d = 0.f;
#pragma unroll
            for (int k = 0; k < 8; k++) d += prt2[wid * 2 + 1][lane + 64 * k];
#pragma unroll
            for (int o = 32; o; o >>= 1) d += __shfl_xor(d, o, 64);
            d1 = d;
        }
    }
    if (lane < 32) {
        int rr = lane >> 4;  // 0: row 2wid (lanes 0-15), 1: row 2wid+1 (lanes 16-31)
        int row = wid * 2 + rr;
        float m = rr ? m1 : m0;
        float oR = one_r[r0 + row];
        float roi = ro[r0 + row];
        float z = roi - m * oR * 0.5f;  // ro - ro_max/ALPHA
        int kk = lane & 15;
        float term = tg[3 * kk] * sigf(tg[3 * kk + 1] * z + tg[3 * kk + 2]);
        term += __shfl_down(term, 8, 16);
        term += __shfl_down(term, 4, 16);
        term += __shfl_down(term, 2, 16);
        term += __shfl_down(term, 1, 16);
        if (kk == 0) {
            float yd = term * oR;
            float yn = (y[r0 + row] + yd) * oR;
            y[r0 + row] = yn;
            ydl[row] = yd;
            ydrol[row] = yd / roi;
            if (FINAL) {
                float dd = rr ? d1 : d0;
                out[NCOLS + r0 + row] = yn + rm[r0 + row] + dd;  // pred_dual
            }
        }
    }
    __syncthreads();
    float s1[8], s2[8];
#pragma unroll
    for (int c = 0; c < 8; c++) { s1[c] = 0.f; s2[c] = 0.f; }
#pragma unroll
    for (int i = 0; i < RPB; i++) {
        float a[8];
        unpack8(w[i], a);
        float u = ydl[i];
        float q = ydrol[i];
#pragma unroll
        for (int c = 0; c < 8; c++) {
            s1[c] += a[c] * u;
            s2[c] += a[c] * q;
        }
    }
    float4* q1 = reinterpret_cast<float4*>(p1 + (size_t)s * NCOLS + 8 * t);
    float4* q2 = reinterpret_cast<float4*>(p2 + (size_t)s * NCOLS + 8 * t);
    q1[0] = make_float4(s1[0], s1[1], s1[2], s1[3]);
    q1[1] = make_float4(s1[4], s1[5], s1[6], s1[7]);
    q2[0] = make_float4(s2[0], s2[1], s2[2], s2[3]);
    q2[1] = make_float4(s2[4], s2[5], s2[6], s2[7]);
}

// ---------------- stage-2 reductions (parallel over splits) ----------------
// 256 blocks x 256 threads (1 block/CU); 16 columns/block; 16 groups x 16 splits.

__global__ __launch_bounds__(256) void k_left(const float* __restrict__ p1,
                                              const float* __restrict__ p2,
                                              const float* __restrict__ thql,
                                              const float* __restrict__ h,
                                              const float* __restrict__ fptr,
                                              float* __restrict__ one_l,
                                              float* __restrict__ hw,
                                              float* __restrict__ r,
                                              float* __restrict__ b,
                                              float* __restrict__ x) {
    __shared__ float smS[256];
    __shared__ float smM[256];
    int jl = threadIdx.x & 15;
    int g = threadIdx.x >> 4;  // 0..15
    int j = blockIdx.x * 16 + jl;
    float cs = 0.f, cm = -INFINITY;
#pragma unroll
    for (int t = 0; t < S2SP; t++) {
        int s = g * S2SP + t;
        cs += p1[(size_t)s * NCOLS + j];
        cm = fmaxf(cm, p2[(size_t)s * NCOLS + j]);
    }
    smS[threadIdx.x] = cs;
    smM[threadIdx.x] = cm;
    __syncthreads();
    if (g == 0) {
#pragma unroll
        for (int gg = 1; gg < 16; gg++) {
            cs += smS[gg * 16 + jl];
            cm = fmaxf(cm, smM[gg * 16 + jl]);
        }
        float q = 0.f;
#pragma unroll
        for (int k = 0; k < 4; k++) q += sigf(thql[2 * k] * cs + thql[2 * k + 1]);
        float c1 = q * 0.25f;
        float lm = fmaxf(c1, cm);
        one_l[j] = 1.0f - lm;
        hw[j] = h[j] * lm / cs;
        r[j] = fptr[0];
        b[j] = 1.0f;
        x[j] = 0.f;
    }
}

__global__ __launch_bounds__(256) void k_rot(const float* __restrict__ p,
                                             const float* __restrict__ one_l,
                                             float* __restrict__ ro_t) {
    __shared__ float smM[256];
    int jl = threadIdx.x & 15;
    int g = threadIdx.x >> 4;
    int j = blockIdx.x * 16 + jl;
    float m = -INFINITY;
#pragma unroll
    for (int t = 0; t < S2SP; t++) {
        int s = g * S2SP + t;
        m = fmaxf(m, p[(size_t)s * NCOLS + j]);
    }
    smM[threadIdx.x] = m;
    __syncthreads();
    if (g == 0) {
#pragma unroll
        for (int gg = 1; gg < 16; gg++) m = fmaxf(m, smM[gg * 16 + jl]);
        ro_t[j] = m * one_l[j];
    }
}

__global__ __launch_bounds__(256) void k_epilogue(const float* __restrict__ p1,
                                                  const float* __restrict__ p2,
                                                  const float* __restrict__ one_l,
                                                  const float* __restrict__ tb,
                                                  const float* __restrict__ fptr,
                                                  float* __restrict__ r,
                                                  float* __restrict__ b,
                                                  float* __restrict__ x,
                                                  float* __restrict__ out, int last) {
    __shared__ float smA[256];
    __shared__ float smB[256];
    int jl = threadIdx.x & 15;
    int g = threadIdx.x >> 4;
    int j = blockIdx.x * 16 + jl;
    float s1 = 0.f, s2 = 0.f;
#pragma unroll
    for (int t = 0; t < S2SP; t++) {
        int s = g * S2SP + t;
        s1 += p1[(size_t)s * NCOLS + j];
        s2 += p2[(size_t)s * NCOLS + j];
    }
    smA[threadIdx.x] = s1;
    smB[threadIdx.x] = s2;
    __syncthreads();
    if (g == 0) {
#pragma unroll
        for (int gg = 1; gg < 16; gg++) {
            s1 += smA[gg * 16 + jl];
            s2 += smB[gg * 16 + jl];
        }
        float oL = one_l[j];
        float rj = (r[j] - fmaxf(s1, 0.f)) * oL;
        float xj = (x[j] + b[j] * s2) * oL;
        float fv = fptr[0];
        float bb = 0.f;
#pragma unroll
        for (int k = 0; k < 16; k++) {
            float ak = tb[4 * k], bk = tb[4 * k + 1], ck = tb[4 * k + 2],
                  dk = tb[4 * k + 3];
            bb += ak * sigf(bk * rj + ck) * exp2f(-fmaxf(dk * (rj - fv), 0.f));
        }
        r[j] = rj;
        x[j] = xj;
        if (last) out[j] = xj;  // pred_primal
        b[j] = bb * oL;
    }
}

extern "C" void kernel_launch(void* const* d_in, const int* in_sizes, int n_in,
                              void* d_out, int out_size, void* d_ws, size_t ws_size,
                              hipStream_t stream) {
    const float* A = (const float*)d_in[0];
    const float* theta_g = (const float*)d_in[1];  // (5,16,3)
    const float* theta_b = (const float*)d_in[2];  // (5,16,4)
    const float* fptr = (const float*)d_in[3];     // scalar
    const float* h = (const float*)d_in[4];        // (N,)
    const float* thql = (const float*)d_in[5];     // (4,2)
    const float* thqr = (const float*)d_in[6];     // (4,2)
    float* out = (float*)d_out;  // [0:4096]=pred_primal(x), [4096:8192]=pred_dual

    // workspace layout (floats)
    float* ws = (float*)d_ws;
    float* right_mask = ws + 0 * 4096;
    float* one_r = ws + 1 * 4096;
    float* one_l = ws + 2 * 4096;
    float* hwv = ws + 3 * 4096;
    float* ro = ws + 4 * 4096;
    float* ro_t = ws + 5 * 4096;
    float* r = ws + 6 * 4096;
    float* b = ws + 7 * 4096;
    float* x = ws + 8 * 4096;
    float* y = ws + 9 * 4096;
    float* p1 = ws + 12 * 4096;
    float* p2 = p1 + (size_t)NSPLIT * NCOLS;
    unsigned* Abf = (unsigned*)(p2 + (size_t)NSPLIT * NCOLS);  // 32 MB bf16 copy

    // preamble: ONE pass over fp32 A (convert + rowsum/right_mask + col partials)
    k_pre_fused<<<NSPLIT, 512, 0, stream>>>(A, Abf, thqr, right_mask, one_r, y, p1, p2);
    k_left<<<256, 256, 0, stream>>>(p1, p2, thql, h, fptr, one_l, hwv, r, b, x);

    // layers: last k_row_dual also emits pred_dual; last epilogue emits pred_primal
    for (int l = 0; l < NLAYERS; l++) {
        k_ro_colmax<<<NSPLIT, 512, 0, stream>>>(Abf, b, one_r, ro, p1);
        k_rot<<<256, 256, 0, stream>>>(p1, one_l, ro_t);
        if (l < NLAYERS - 1)
            k_row_dual<0><<<NSPLIT, 512, 0, stream>>>(Abf, ro_t, one_r, ro,
                                                      theta_g + l * 48, y, p1, p2, hwv,
                                                      right_mask, out);
        else
            k_row_dual<1><<<NSPLIT, 512, 0, stream>>>(Abf, ro_t, one_r, ro,
                                                      theta_g + l * 48, y, p1, p2, hwv,
                                                      right_mask, out);
        k_epilogue<<<256, 256, 0, stream>>>(p1, p2, one_l, theta_b + l * 64, fptr, r, b,
                                            x, out, l == NLAYERS - 1);
    }
}